// Round 3
// baseline (7967.088 us; speedup 1.0000x reference)
//
#include <hip/hip_runtime.h>
#include <hip/hip_bf16.h>

#define HH 1024
#define BATCH 32
#define SSRC 256
#define SDEC 64
#define EDIM 512
#define VOC 32000
#define NBLK 256

typedef __attribute__((ext_vector_type(8))) short bf16x8_t;
typedef __attribute__((ext_vector_type(4))) float f32x4_t;

__device__ __forceinline__ float bf2f(unsigned short u) {
  union { float f; unsigned int i; } c; c.i = ((unsigned int)u) << 16; return c.f;
}
__device__ __forceinline__ unsigned short f2bf(float f) {
  union { float f; unsigned int i; } c; c.f = f;
  unsigned int r = c.i + 0x7fffu + ((c.i >> 16) & 1u);
  return (unsigned short)(r >> 16);
}
__device__ __forceinline__ f32x4_t mfma16(bf16x8_t a, bf16x8_t b, f32x4_t c) {
  return __builtin_amdgcn_mfma_f32_16x16x32_bf16(a, b, c, 0, 0, 0);
}

// ---- flag-array grid barrier: each block owns flags[bid*16]; poll all 256 ----
__device__ __forceinline__ void pollbar(const unsigned* flags, unsigned g1) {
  if (threadIdx.x < 64) {
    const int l = threadIdx.x;
    unsigned a, b, c, d;
    do {
      a = __hip_atomic_load(&flags[l * 16], __ATOMIC_RELAXED, __HIP_MEMORY_SCOPE_AGENT);
      b = __hip_atomic_load(&flags[(l + 64) * 16], __ATOMIC_RELAXED, __HIP_MEMORY_SCOPE_AGENT);
      c = __hip_atomic_load(&flags[(l + 128) * 16], __ATOMIC_RELAXED, __HIP_MEMORY_SCOPE_AGENT);
      d = __hip_atomic_load(&flags[(l + 192) * 16], __ATOMIC_RELAXED, __HIP_MEMORY_SCOPE_AGENT);
      if (__all(a >= g1 && b >= g1 && c >= g1 && d >= g1)) break;
      __builtin_amdgcn_s_sleep(1);
    } while (1);
  }
  if (threadIdx.x == 0) __threadfence();  // acquire: invalidate stale L1/L2
  __syncthreads();
}
__device__ __forceinline__ void arrive(unsigned* flags, unsigned g1, int bid) {
  __syncthreads();  // per-wave vmcnt drain before publishing
  if (threadIdx.x == 0) {
    __threadfence();  // write-back local L2 so remote XCDs see our stores
    __hip_atomic_store(&flags[bid * 16], g1, __ATOMIC_RELEASE, __HIP_MEMORY_SCOPE_AGENT);
  }
}

// ---------- transpose f32 (K,N) -> bf16 (N,K) ----------
__global__ void k_transpose_bf16(const float* __restrict__ in, unsigned short* __restrict__ out,
                                 int K, int N) {
  __shared__ float tile[32][33];
  int n0 = blockIdx.x * 32, k0 = blockIdx.y * 32;
  int tx = threadIdx.x, ty = threadIdx.y;
#pragma unroll
  for (int i = 0; i < 4; i++)
    tile[ty + i * 8][tx] = in[(size_t)(k0 + ty + i * 8) * N + (n0 + tx)];
  __syncthreads();
#pragma unroll
  for (int i = 0; i < 4; i++)
    out[(size_t)(n0 + ty + i * 8) * K + (k0 + tx)] = f2bf(tile[tx][ty + i * 8]);
}

// ---------- elementwise cast f32 -> bf16 ----------
__global__ void k_cast_bf16(const float* __restrict__ in, unsigned short* __restrict__ out, int n) {
  int i = (blockIdx.x * blockDim.x + threadIdx.x) * 4;
  if (i < n) {
    float4 v = *(const float4*)(in + i);
    out[i] = f2bf(v.x); out[i + 1] = f2bf(v.y); out[i + 2] = f2bf(v.z); out[i + 3] = f2bf(v.w);
  }
}

// ---------- embedding gather -> bf16 ----------
__global__ void k_embed(const int* __restrict__ seq, const float* __restrict__ emb,
                        unsigned short* __restrict__ out) {
  int t = blockIdx.x;
  int row = seq[t];
  const float* s = emb + (size_t)row * EDIM;
  unsigned short* d = out + (size_t)t * EDIM;
  for (int e = threadIdx.x; e < EDIM; e += blockDim.x) d[e] = f2bf(s[e]);
}

// ---------- big GEMM: C[M,N] = A[M,K](bf16) * B^T[N,K](bf16) + bias ----------
template <int OUT_BF16>
__global__ __launch_bounds__(256) void k_gemm_bt(const unsigned short* __restrict__ A,
                                                 const unsigned short* __restrict__ B,
                                                 const float* __restrict__ bias,
                                                 void* __restrict__ Cv, int M, int N, int K) {
  __shared__ unsigned short As[128 * 32];
  __shared__ unsigned short Bs[128 * 32];
  const int tid = threadIdx.x;
  const int wave = tid >> 6, lane = tid & 63;
  const int row0 = blockIdx.y * 128, col0 = blockIdx.x * 128;
  const int wr = (wave >> 1) * 64, wc = (wave & 1) * 64;
  const int lrow = lane & 15, lk8 = (lane >> 4) * 8;
  f32x4_t acc[4][4] = {};
  const int c1 = wave, c2 = wave + 4;
  const int sr1 = c1 * 16 + (lane >> 2), sr2 = c2 * 16 + (lane >> 2);
  const int sk = (lane & 3) * 8;
  for (int kt = 0; kt < K; kt += 32) {
    __builtin_amdgcn_global_load_lds(
        (const __attribute__((address_space(1))) unsigned int*)(A + (size_t)(row0 + sr1) * K + kt + sk),
        (__attribute__((address_space(3))) unsigned int*)(As + c1 * 512), 16, 0, 0);
    __builtin_amdgcn_global_load_lds(
        (const __attribute__((address_space(1))) unsigned int*)(A + (size_t)(row0 + sr2) * K + kt + sk),
        (__attribute__((address_space(3))) unsigned int*)(As + c2 * 512), 16, 0, 0);
    __builtin_amdgcn_global_load_lds(
        (const __attribute__((address_space(1))) unsigned int*)(B + (size_t)(col0 + sr1) * K + kt + sk),
        (__attribute__((address_space(3))) unsigned int*)(Bs + c1 * 512), 16, 0, 0);
    __builtin_amdgcn_global_load_lds(
        (const __attribute__((address_space(1))) unsigned int*)(B + (size_t)(col0 + sr2) * K + kt + sk),
        (__attribute__((address_space(3))) unsigned int*)(Bs + c2 * 512), 16, 0, 0);
    __syncthreads();
    bf16x8_t af[4], bfr[4];
#pragma unroll
    for (int i = 0; i < 4; i++) {
      af[i] = *(const bf16x8_t*)(As + (wr + i * 16 + lrow) * 32 + lk8);
      bfr[i] = *(const bf16x8_t*)(Bs + (wc + i * 16 + lrow) * 32 + lk8);
    }
#pragma unroll
    for (int i = 0; i < 4; i++)
#pragma unroll
      for (int j = 0; j < 4; j++) acc[i][j] = mfma16(af[i], bfr[j], acc[i][j]);
    __syncthreads();
  }
#pragma unroll
  for (int j = 0; j < 4; j++) {
    int col = col0 + wc + j * 16 + lrow;
    float bv = bias ? bias[col] : 0.0f;
#pragma unroll
    for (int i = 0; i < 4; i++) {
#pragma unroll
      for (int r = 0; r < 4; r++) {
        int row = row0 + wr + i * 16 + (lane >> 4) * 4 + r;
        float v = acc[i][j][r] + bv;
        if (OUT_BF16)
          ((unsigned short*)Cv)[(size_t)row * N + col] = f2bf(v);
        else
          ((float*)Cv)[(size_t)row * N + col] = v;
      }
    }
  }
}

// ---------- persistent encoder: 256 blocks x 4 cols, 1 flag-bar/step ----------
__global__ __launch_bounds__(512, 1) void k_enc_scan2(
    const unsigned short* __restrict__ gx,    // [32][256][3072]
    const unsigned short* __restrict__ WhT,   // [3072][1024]
    unsigned short* __restrict__ ench,        // [32][256][1024]
    unsigned short* __restrict__ hg,          // [2][32][1024]
    float* __restrict__ h0f,                  // [32][1024]
    unsigned* __restrict__ flags) {
  __shared__ __align__(16) unsigned short wh[16 * 1024];  // rows g*4+c, XOR-swizzled
  __shared__ float gsum[4][2][16][16];                    // [kq][mt][row][col]
  __shared__ float hp[32][4];
  const int tid = threadIdx.x, bid = blockIdx.x;
  const int lane = tid & 63, wave = tid >> 6;
  const int j0 = bid * 4;
  const int mt = wave & 1, kq = wave >> 1;
  const int lrow = lane & 15, lk = (lane >> 4) * 8;
  for (int i = tid; i < 2048; i += 512) {
    int r = i >> 7, k8 = (i & 127) * 8;
    bf16x8_t v = {};
    if (r < 12) {
      int g3 = r >> 2, c = r & 3;
      v = *(const bf16x8_t*)(WhT + (size_t)(g3 * HH + j0 + c) * HH + k8);
    }
    int byt = ((r * HH + k8) * 2) ^ ((r & 7) << 4);
    *(bf16x8_t*)((char*)wh + byt) = v;
  }
  if (tid < 128) hp[tid >> 2][tid & 3] = 0.0f;
  __syncthreads();
  for (int t = 0; t < SSRC; ++t) {
    const unsigned short* hsrc = hg + (size_t)(t & 1) * (32 * HH);
    f32x4_t acc = {};
    if (t > 0) {
      const int row = mt * 16 + lrow;
#pragma unroll
      for (int ks = 0; ks < 8; ++ks) {
        int k = kq * 256 + ks * 32 + lk;
        bf16x8_t x = *(const bf16x8_t*)(hsrc + (size_t)row * HH + k);
        int byt = ((lrow * HH + k) * 2) ^ ((lrow & 7) << 4);
        bf16x8_t w8 = *(const bf16x8_t*)((const char*)wh + byt);
        acc = mfma16(x, w8, acc);
      }
    }
#pragma unroll
    for (int r = 0; r < 4; ++r) gsum[kq][mt][(lane >> 4) * 4 + r][lane & 15] = acc[r];
    __syncthreads();
    if (tid < 128) {
      int b = tid >> 2, c = tid & 3;
      float s0 = 0, s1 = 0, s2 = 0;
#pragma unroll
      for (int q = 0; q < 4; ++q) {
        s0 += gsum[q][b >> 4][b & 15][c];
        s1 += gsum[q][b >> 4][b & 15][4 + c];
        s2 += gsum[q][b >> 4][b & 15][8 + c];
      }
      const unsigned short* gxp = gx + ((size_t)b * SSRC + t) * (3 * HH) + j0 + c;
      float xz = bf2f(gxp[0]), xr = bf2f(gxp[HH]), xh = bf2f(gxp[2 * HH]);
      float z = 1.f / (1.f + expf(-(xz + s0)));
      float r = 1.f / (1.f + expf(-(xr + s1)));
      float cand = tanhf(xh + r * s2);
      float hn = z * hp[b][c] + (1.f - z) * cand;
      hp[b][c] = hn;
      unsigned short hv = f2bf(hn);
      hg[(size_t)((t + 1) & 1) * (32 * HH) + b * HH + j0 + c] = hv;
      ench[((size_t)b * SSRC + t) * HH + j0 + c] = hv;
      if (t == SSRC - 1) h0f[b * HH + j0 + c] = hn;
    }
    arrive(flags, t + 1, bid);
    if (t < SSRC - 1) pollbar(flags, t + 1);
  }
}

// ---------- persistent decoder: 256 blocks, GEMM+attention fused, 2 flag-bars/step ----------
__global__ __launch_bounds__(512, 1) void k_dec_scan2(
    const unsigned short* __restrict__ xpart,  // [32][64][3072]
    const unsigned short* __restrict__ WhDT,   // [3072][1024]
    const unsigned short* __restrict__ WxD2T,  // [3072][1024]
    const unsigned short* __restrict__ ench,   // [32][256][1024]
    const unsigned short* __restrict__ encW,   // [32][256][1024]
    const float* __restrict__ h0f,
    unsigned short* __restrict__ hg,           // [2][32][1024] (parity continues from encoder)
    float* __restrict__ ctxf,                  // [2][32][1024] f32, unnormalized
    float* __restrict__ denom,                 // [2][32]
    unsigned short* __restrict__ deco,         // [32][64][1024]
    unsigned* __restrict__ flags) {
  __shared__ __align__(16) unsigned short wh[16 * 1024];
  __shared__ __align__(16) unsigned short wx[16 * 1024];
  __shared__ __align__(16) unsigned short ew[32 * 1024];
  __shared__ __align__(16) unsigned short hb[HH];
  __shared__ float wt[32];
  __shared__ float gsh[4][2][16][16];
  __shared__ float gsc[4][2][16][16];
  __shared__ float hp[32][4];
  const int tid = threadIdx.x, bid = blockIdx.x;
  const int lane = tid & 63, wave = tid >> 6;
  const int j0 = bid * 4;
  const int ab = bid >> 3, s0 = (bid & 7) * 32;  // attention duty
  const int mt = wave & 1, kq = wave >> 1;
  const int lrow = lane & 15, lk = (lane >> 4) * 8;
  for (int i = tid; i < 2048; i += 512) {
    int r = i >> 7, k8 = (i & 127) * 8;
    bf16x8_t vh = {}, vx = {};
    if (r < 12) {
      int g3 = r >> 2, c = r & 3;
      size_t off = (size_t)(g3 * HH + j0 + c) * HH + k8;
      vh = *(const bf16x8_t*)(WhDT + off);
      vx = *(const bf16x8_t*)(WxD2T + off);
    }
    int byt = ((r * HH + k8) * 2) ^ ((r & 7) << 4);
    *(bf16x8_t*)((char*)wh + byt) = vh;
    *(bf16x8_t*)((char*)wx + byt) = vx;
  }
  for (int i = tid; i < 4096; i += 512) {
    int r = i >> 7, k8 = (i & 127) * 8;
    *(bf16x8_t*)(ew + r * HH + k8) =
        *(const bf16x8_t*)(encW + ((size_t)ab * SSRC + s0 + r) * HH + k8);
  }
  if (tid < 128) hp[tid >> 2][tid & 3] = h0f[(tid >> 2) * HH + j0 + (tid & 3)];
  __syncthreads();
  unsigned gf = 0;
  for (int t = 0; t < SDEC; ++t) {
    const int cur = t & 1, nxt = cur ^ 1;
    const unsigned short* hsrc = hg + (size_t)cur * (32 * HH);
    // ---- phase A: scores -> exp-weights -> atomic partial ctx/denom ----
    if (tid < 128) *(bf16x8_t*)(hb + tid * 8) = *(const bf16x8_t*)(hsrc + ab * HH + tid * 8);
    __syncthreads();
    {
      int srow = wave * 4 + (lane >> 4);
      const unsigned short* er = ew + srow * HH;
      float dacc = 0.f;
#pragma unroll
      for (int it = 0; it < 8; ++it) {
        int k = it * 128 + (lane & 15) * 8;
        bf16x8_t e = *(const bf16x8_t*)(er + k);
        bf16x8_t h8 = *(const bf16x8_t*)(hb + k);
#pragma unroll
        for (int u = 0; u < 8; ++u)
          dacc += bf2f((unsigned short)e[u]) * bf2f((unsigned short)h8[u]);
      }
#pragma unroll
      for (int m = 1; m < 16; m <<= 1) dacc += __shfl_xor(dacc, m);
      if ((lane & 15) == 0) wt[srow] = expf(dacc);  // scores ~ +-0.3: no max needed
    }
    __syncthreads();
    if (tid == 0) {
      float ds = 0.f;
#pragma unroll
      for (int s = 0; s < 32; ++s) ds += wt[s];
      unsafeAtomicAdd(&denom[cur * 32 + ab], ds);
    }
    {
      int k2 = tid * 2;
      float a0 = 0.f, a1 = 0.f;
      const unsigned short* eb = ench + ((size_t)ab * SSRC + s0) * HH + k2;
#pragma unroll 4
      for (int s = 0; s < 32; ++s) {
        float w = wt[s];
        unsigned int pk = *(const unsigned int*)(eb + (size_t)s * HH);
        a0 += w * bf2f((unsigned short)(pk & 0xffffu));
        a1 += w * bf2f((unsigned short)(pk >> 16));
      }
      float* cp = ctxf + (size_t)cur * (32 * HH) + ab * HH + k2;
      unsafeAtomicAdd(cp, a0);
      unsafeAtomicAdd(cp + 1, a1);
    }
    arrive(flags, gf + 1, bid);
    // gh_h GEMM hidden under barrier latency (block-local result in LDS)
    {
      f32x4_t acc = {};
      const int row = mt * 16 + lrow;
#pragma unroll
      for (int ks = 0; ks < 8; ++ks) {
        int k = kq * 256 + ks * 32 + lk;
        bf16x8_t x = *(const bf16x8_t*)(hsrc + (size_t)row * HH + k);
        int byt = ((lrow * HH + k) * 2) ^ ((lrow & 7) << 4);
        bf16x8_t w8 = *(const bf16x8_t*)((const char*)wh + byt);
        acc = mfma16(x, w8, acc);
      }
#pragma unroll
      for (int r = 0; r < 4; ++r) gsh[kq][mt][(lane >> 4) * 4 + r][lane & 15] = acc[r];
    }
    pollbar(flags, gf + 1);
    gf++;
    // ---- phase B: gh_c = ctx_unnorm @ WxD2, gates, h update ----
    {
      f32x4_t acc = {};
      const int row = mt * 16 + lrow;
      const float* cbase = ctxf + (size_t)cur * (32 * HH) + (size_t)row * HH;
#pragma unroll
      for (int ks = 0; ks < 8; ++ks) {
        int k = kq * 256 + ks * 32 + lk;
        float4 f0 = *(const float4*)(cbase + k);
        float4 f1 = *(const float4*)(cbase + k + 4);
        bf16x8_t x;
        x[0] = (short)f2bf(f0.x); x[1] = (short)f2bf(f0.y);
        x[2] = (short)f2bf(f0.z); x[3] = (short)f2bf(f0.w);
        x[4] = (short)f2bf(f1.x); x[5] = (short)f2bf(f1.y);
        x[6] = (short)f2bf(f1.z); x[7] = (short)f2bf(f1.w);
        int byt = ((lrow * HH + k) * 2) ^ ((lrow & 7) << 4);
        bf16x8_t w8 = *(const bf16x8_t*)((const char*)wx + byt);
        acc = mfma16(x, w8, acc);
      }
#pragma unroll
      for (int r = 0; r < 4; ++r) gsc[kq][mt][(lane >> 4) * 4 + r][lane & 15] = acc[r];
    }
    __syncthreads();
    if (tid < 128) {
      int b = tid >> 2, c = tid & 3;
      float dv = denom[cur * 32 + b];
      float h0 = 0, h1 = 0, h2 = 0, c0 = 0, c1 = 0, c2 = 0;
#pragma unroll
      for (int q = 0; q < 4; ++q) {
        h0 += gsh[q][b >> 4][b & 15][c];
        h1 += gsh[q][b >> 4][b & 15][4 + c];
        h2 += gsh[q][b >> 4][b & 15][8 + c];
        c0 += gsc[q][b >> 4][b & 15][c];
        c1 += gsc[q][b >> 4][b & 15][4 + c];
        c2 += gsc[q][b >> 4][b & 15][8 + c];
      }
      float inv = 1.f / dv;
      const unsigned short* xp = xpart + ((size_t)b * SDEC + t) * (3 * HH) + j0 + c;
      float xz = bf2f(xp[0]) + c0 * inv;
      float xr = bf2f(xp[HH]) + c1 * inv;
      float xh = bf2f(xp[2 * HH]) + c2 * inv;
      float z = 1.f / (1.f + expf(-(xz + h0)));
      float r = 1.f / (1.f + expf(-(xr + h1)));
      float cand = tanhf(xh + r * h2);
      float hn = z * hp[b][c] + (1.f - z) * cand;
      hp[b][c] = hn;
      unsigned short hv = f2bf(hn);
      hg[(size_t)nxt * (32 * HH) + b * HH + j0 + c] = hv;
      deco[((size_t)b * SDEC + t) * HH + j0 + c] = hv;
    }
    // zero next-step ctx/denom (consumed two bars ago -> safe)
    if (tid < 128) ctxf[(size_t)nxt * (32 * HH) + bid * 128 + tid] = 0.f;
    if (bid < 32 && tid == 0) denom[nxt * 32 + bid] = 0.f;
    arrive(flags, gf + 1, bid);
    if (t < SDEC - 1) pollbar(flags, gf + 1);
    gf++;
  }
}

extern "C" void kernel_launch(void* const* d_in, const int* in_sizes, int n_in,
                              void* d_out, int out_size, void* d_ws, size_t ws_size,
                              hipStream_t stream) {
  const int* src_seq = (const int*)d_in[0];
  const int* dec_seq = (const int*)d_in[1];
  const float* emb = (const float*)d_in[2];
  const float* Wx_enc = (const float*)d_in[3];
  const float* Wh_enc = (const float*)d_in[4];
  const float* b_enc = (const float*)d_in[5];
  const float* Wx_dec = (const float*)d_in[6];
  const float* Wh_dec = (const float*)d_in[7];
  const float* b_dec = (const float*)d_in[8];
  const float* W_att = (const float*)d_in[9];
  const float* W_out = (const float*)d_in[10];
  const float* b_out = (const float*)d_in[11];

  // Single-phase scratch in d_out (~128 MB < 262 MB; overwritten by final GEMM).
  char* ob = (char*)d_out;
  size_t oo = 0;
  auto oalloc = [&](size_t bytes) {
    char* p = ob + oo;
    oo += (bytes + 255) & ~(size_t)255;
    return p;
  };
  unsigned short* WxTe = (unsigned short*)oalloc((size_t)3 * HH * EDIM * 2);
  unsigned short* WhTe = (unsigned short*)oalloc((size_t)3 * HH * HH * 2);
  unsigned short* WxD1T = (unsigned short*)oalloc((size_t)3 * HH * EDIM * 2);
  unsigned short* WxD2T = (unsigned short*)oalloc((size_t)3 * HH * HH * 2);
  unsigned short* WhDT = (unsigned short*)oalloc((size_t)3 * HH * HH * 2);
  unsigned short* Wattb = (unsigned short*)oalloc((size_t)HH * HH * 2);
  unsigned short* src_e = (unsigned short*)oalloc((size_t)BATCH * SSRC * EDIM * 2);
  unsigned short* dec_e = (unsigned short*)oalloc((size_t)BATCH * SDEC * EDIM * 2);
  unsigned short* gx_enc = (unsigned short*)oalloc((size_t)BATCH * SSRC * 3 * HH * 2);
  unsigned short* xpart = (unsigned short*)oalloc((size_t)BATCH * SDEC * 3 * HH * 2);
  unsigned short* ench = (unsigned short*)oalloc((size_t)BATCH * SSRC * HH * 2);
  unsigned short* encW = (unsigned short*)oalloc((size_t)BATCH * SSRC * HH * 2);

  // Alive during final GEMM -> d_ws (~70 MB).
  char* wb = (char*)d_ws;
  size_t wo = 0;
  auto walloc = [&](size_t bytes) {
    char* p = wb + wo;
    wo += (bytes + 255) & ~(size_t)255;
    return p;
  };
  unsigned short* WoutT = (unsigned short*)walloc((size_t)VOC * HH * 2);
  unsigned short* deco = (unsigned short*)walloc((size_t)BATCH * SDEC * HH * 2);
  unsigned short* hg = (unsigned short*)walloc((size_t)2 * BATCH * HH * 2);
  float* h0f = (float*)walloc(BATCH * HH * 4);
  float* ctxf = (float*)walloc((size_t)2 * BATCH * HH * 4);
  float* denom = (float*)walloc(2 * 32 * 4);
  unsigned* flags_e = (unsigned*)walloc(NBLK * 16 * 4);
  unsigned* flags_d = (unsigned*)walloc(NBLK * 16 * 4);
  if (wo > ws_size) return;

  dim3 tb(32, 8);
  k_transpose_bf16<<<dim3(3 * HH / 32, EDIM / 32), tb, 0, stream>>>(Wx_enc, WxTe, EDIM, 3 * HH);
  k_transpose_bf16<<<dim3(3 * HH / 32, HH / 32), tb, 0, stream>>>(Wh_enc, WhTe, HH, 3 * HH);
  k_transpose_bf16<<<dim3(3 * HH / 32, EDIM / 32), tb, 0, stream>>>(Wx_dec, WxD1T, EDIM, 3 * HH);
  k_transpose_bf16<<<dim3(3 * HH / 32, HH / 32), tb, 0, stream>>>(Wx_dec + (size_t)EDIM * 3 * HH,
                                                                  WxD2T, HH, 3 * HH);
  k_transpose_bf16<<<dim3(3 * HH / 32, HH / 32), tb, 0, stream>>>(Wh_dec, WhDT, HH, 3 * HH);
  k_transpose_bf16<<<dim3(VOC / 32, HH / 32), tb, 0, stream>>>(W_out, WoutT, HH, VOC);
  k_cast_bf16<<<(HH * HH / 4) / 256, 256, 0, stream>>>(W_att, Wattb, HH * HH);

  k_embed<<<BATCH * SSRC, 128, 0, stream>>>(src_seq, emb, src_e);
  k_embed<<<BATCH * SDEC, 128, 0, stream>>>(dec_seq, emb, dec_e);

  k_gemm_bt<1><<<dim3(3 * HH / 128, BATCH * SSRC / 128), 256, 0, stream>>>(
      src_e, WxTe, b_enc, gx_enc, BATCH * SSRC, 3 * HH, EDIM);
  k_gemm_bt<1><<<dim3(3 * HH / 128, BATCH * SDEC / 128), 256, 0, stream>>>(
      dec_e, WxD1T, b_dec, xpart, BATCH * SDEC, 3 * HH, EDIM);

  hipMemsetAsync(hg, 0, (size_t)BATCH * HH * 2, stream);          // hg[0] = h0 = 0
  hipMemsetAsync(ctxf, 0, (size_t)2 * BATCH * HH * 4, stream);
  hipMemsetAsync(denom, 0, 2 * 32 * 4, stream);
  hipMemsetAsync(flags_e, 0, NBLK * 16 * 4 * 2, stream);          // both flag arrays

  k_enc_scan2<<<NBLK, 512, 0, stream>>>(gx_enc, WhTe, ench, hg, h0f, flags_e);

  // encW[b,s,k] = sum_j ench[b,s,j] * W_att[k,j]  (scores reassociation)
  k_gemm_bt<1><<<dim3(HH / 128, BATCH * SSRC / 128), 256, 0, stream>>>(
      ench, Wattb, nullptr, encW, BATCH * SSRC, HH, HH);

  k_dec_scan2<<<NBLK, 512, 0, stream>>>(xpart, WhDT, WxD2T, ench, encW, h0f, hg, ctxf, denom,
                                        deco, flags_d);

  k_gemm_bt<0><<<dim3(VOC / 128, BATCH * SDEC / 128), 256, 0, stream>>>(
      deco, WoutT, b_out, d_out, BATCH * SDEC, VOC, HH);
}

// Round 4
// 3539.542 us; speedup vs baseline: 2.2509x; 2.2509x over previous
//
#include <hip/hip_runtime.h>
#include <hip/hip_bf16.h>

#define HH 1024
#define BATCH 32
#define SSRC 256
#define SDEC 64
#define EDIM 512
#define VOC 32000
#define NBLK 256

typedef __attribute__((ext_vector_type(8))) short bf16x8_t;
typedef __attribute__((ext_vector_type(4))) float f32x4_t;

__device__ __forceinline__ float bf2f(unsigned short u) {
  union { float f; unsigned int i; } c; c.i = ((unsigned int)u) << 16; return c.f;
}
__device__ __forceinline__ unsigned short f2bf(float f) {
  union { float f; unsigned int i; } c; c.f = f;
  unsigned int r = c.i + 0x7fffu + ((c.i >> 16) & 1u);
  return (unsigned short)(r >> 16);
}
__device__ __forceinline__ f32x4_t mfma16(bf16x8_t a, bf16x8_t b, f32x4_t c) {
  return __builtin_amdgcn_mfma_f32_16x16x32_bf16(a, b, c, 0, 0, 0);
}

// ---- device-coherent (sc1) accessors: bypass non-coherent per-XCD L2, NO fences ----
__device__ __forceinline__ unsigned long long ald64(const void* p) {
  return __hip_atomic_load((const unsigned long long*)p, __ATOMIC_RELAXED,
                           __HIP_MEMORY_SCOPE_AGENT);
}
__device__ __forceinline__ void ast32(unsigned* p, unsigned v) {
  __hip_atomic_store(p, v, __ATOMIC_RELAXED, __HIP_MEMORY_SCOPE_AGENT);
}
__device__ __forceinline__ unsigned ald32(const unsigned* p) {
  return __hip_atomic_load(p, __ATOMIC_RELAXED, __HIP_MEMORY_SCOPE_AGENT);
}
__device__ __forceinline__ void astf(float* p, float v) {
  __hip_atomic_store(p, v, __ATOMIC_RELAXED, __HIP_MEMORY_SCOPE_AGENT);
}
__device__ __forceinline__ float aldf(const float* p) {
  return __hip_atomic_load(p, __ATOMIC_RELAXED, __HIP_MEMORY_SCOPE_AGENT);
}
__device__ __forceinline__ bf16x8_t ald_bf16x8(const unsigned short* p) {
  union { unsigned long long q[2]; bf16x8_t v; } u;
  u.q[0] = ald64(p);
  u.q[1] = ald64(p + 4);
  return u.v;
}
__device__ __forceinline__ bf16x8_t ald_f32x8_bf(const float* p) {
  union { unsigned long long q; float f[2]; } a, b, c, d;
  a.q = ald64(p); b.q = ald64(p + 2); c.q = ald64(p + 4); d.q = ald64(p + 6);
  bf16x8_t r;
  r[0] = (short)f2bf(a.f[0]); r[1] = (short)f2bf(a.f[1]);
  r[2] = (short)f2bf(b.f[0]); r[3] = (short)f2bf(b.f[1]);
  r[4] = (short)f2bf(c.f[0]); r[5] = (short)f2bf(c.f[1]);
  r[6] = (short)f2bf(d.f[0]); r[7] = (short)f2bf(d.f[1]);
  return r;
}

// ---- fence-free flag barrier: data already at coherence point via sc1 ops ----
__device__ __forceinline__ void arrive(unsigned* flags, unsigned g1) {
  asm volatile("s_waitcnt vmcnt(0)" ::: "memory");  // all my sc1 stores/atomics done
  __syncthreads();                                  // whole block done
  if (threadIdx.x == 0) ast32(&flags[blockIdx.x * 16], g1);
}
__device__ __forceinline__ void pollbar(const unsigned* flags, unsigned g1) {
  if (threadIdx.x < 64) {
    const int l = threadIdx.x;
    while (true) {
      unsigned a = ald32(&flags[l * 16]);
      unsigned b = ald32(&flags[(l + 64) * 16]);
      unsigned c = ald32(&flags[(l + 128) * 16]);
      unsigned d = ald32(&flags[(l + 192) * 16]);
      if (__all((a >= g1) && (b >= g1) && (c >= g1) && (d >= g1))) break;
      __builtin_amdgcn_s_sleep(2);
    }
  }
  __syncthreads();
  asm volatile("" ::: "memory");
}

// ---------- transpose f32 (K,N) -> bf16 (N,K) ----------
__global__ void k_transpose_bf16(const float* __restrict__ in, unsigned short* __restrict__ out,
                                 int K, int N) {
  __shared__ float tile[32][33];
  int n0 = blockIdx.x * 32, k0 = blockIdx.y * 32;
  int tx = threadIdx.x, ty = threadIdx.y;
#pragma unroll
  for (int i = 0; i < 4; i++)
    tile[ty + i * 8][tx] = in[(size_t)(k0 + ty + i * 8) * N + (n0 + tx)];
  __syncthreads();
#pragma unroll
  for (int i = 0; i < 4; i++)
    out[(size_t)(n0 + ty + i * 8) * K + (k0 + tx)] = f2bf(tile[tx][ty + i * 8]);
}

// ---------- elementwise cast f32 -> bf16 ----------
__global__ void k_cast_bf16(const float* __restrict__ in, unsigned short* __restrict__ out, int n) {
  int i = (blockIdx.x * blockDim.x + threadIdx.x) * 4;
  if (i < n) {
    float4 v = *(const float4*)(in + i);
    out[i] = f2bf(v.x); out[i + 1] = f2bf(v.y); out[i + 2] = f2bf(v.z); out[i + 3] = f2bf(v.w);
  }
}

// ---------- embedding gather -> bf16 ----------
__global__ void k_embed(const int* __restrict__ seq, const float* __restrict__ emb,
                        unsigned short* __restrict__ out) {
  int t = blockIdx.x;
  int row = seq[t];
  const float* s = emb + (size_t)row * EDIM;
  unsigned short* d = out + (size_t)t * EDIM;
  for (int e = threadIdx.x; e < EDIM; e += blockDim.x) d[e] = f2bf(s[e]);
}

// ---------- big GEMM: C[M,N] = A[M,K](bf16) * B^T[N,K](bf16) + bias ----------
template <int OUT_BF16>
__global__ __launch_bounds__(256) void k_gemm_bt(const unsigned short* __restrict__ A,
                                                 const unsigned short* __restrict__ B,
                                                 const float* __restrict__ bias,
                                                 void* __restrict__ Cv, int M, int N, int K) {
  __shared__ unsigned short As[128 * 32];
  __shared__ unsigned short Bs[128 * 32];
  const int tid = threadIdx.x;
  const int wave = tid >> 6, lane = tid & 63;
  const int row0 = blockIdx.y * 128, col0 = blockIdx.x * 128;
  const int wr = (wave >> 1) * 64, wc = (wave & 1) * 64;
  const int lrow = lane & 15, lk8 = (lane >> 4) * 8;
  f32x4_t acc[4][4] = {};
  const int c1 = wave, c2 = wave + 4;
  const int sr1 = c1 * 16 + (lane >> 2), sr2 = c2 * 16 + (lane >> 2);
  const int sk = (lane & 3) * 8;
  for (int kt = 0; kt < K; kt += 32) {
    __builtin_amdgcn_global_load_lds(
        (const __attribute__((address_space(1))) unsigned int*)(A + (size_t)(row0 + sr1) * K + kt + sk),
        (__attribute__((address_space(3))) unsigned int*)(As + c1 * 512), 16, 0, 0);
    __builtin_amdgcn_global_load_lds(
        (const __attribute__((address_space(1))) unsigned int*)(A + (size_t)(row0 + sr2) * K + kt + sk),
        (__attribute__((address_space(3))) unsigned int*)(As + c2 * 512), 16, 0, 0);
    __builtin_amdgcn_global_load_lds(
        (const __attribute__((address_space(1))) unsigned int*)(B + (size_t)(col0 + sr1) * K + kt + sk),
        (__attribute__((address_space(3))) unsigned int*)(Bs + c1 * 512), 16, 0, 0);
    __builtin_amdgcn_global_load_lds(
        (const __attribute__((address_space(1))) unsigned int*)(B + (size_t)(col0 + sr2) * K + kt + sk),
        (__attribute__((address_space(3))) unsigned int*)(Bs + c2 * 512), 16, 0, 0);
    __syncthreads();
    bf16x8_t af[4], bfr[4];
#pragma unroll
    for (int i = 0; i < 4; i++) {
      af[i] = *(const bf16x8_t*)(As + (wr + i * 16 + lrow) * 32 + lk8);
      bfr[i] = *(const bf16x8_t*)(Bs + (wc + i * 16 + lrow) * 32 + lk8);
    }
#pragma unroll
    for (int i = 0; i < 4; i++)
#pragma unroll
      for (int j = 0; j < 4; j++) acc[i][j] = mfma16(af[i], bfr[j], acc[i][j]);
    __syncthreads();
  }
#pragma unroll
  for (int j = 0; j < 4; j++) {
    int col = col0 + wc + j * 16 + lrow;
    float bv = bias ? bias[col] : 0.0f;
#pragma unroll
    for (int i = 0; i < 4; i++) {
#pragma unroll
      for (int r = 0; r < 4; r++) {
        int row = row0 + wr + i * 16 + (lane >> 4) * 4 + r;
        float v = acc[i][j][r] + bv;
        if (OUT_BF16)
          ((unsigned short*)Cv)[(size_t)row * N + col] = f2bf(v);
        else
          ((float*)Cv)[(size_t)row * N + col] = v;
      }
    }
  }
}

// Weight-slice LDS staging: 32 rows (tile0: z0-7,r0-7; tile1: hh0-7, zero-pad), swizzled.
// row lr: gate g = lr<8?0 : lr<16?1 : lr<24?2 : none; jj = lr&7.
__device__ __forceinline__ void stage_wslice(unsigned short* wl, const unsigned short* WT,
                                             int j0, int tid) {
  for (int i = tid; i < 32 * 128; i += 512) {
    int lr = i >> 7, k8 = (i & 127) * 8;
    bf16x8_t v = {};
    if (lr < 24) {
      int g = lr >> 3;
      v = *(const bf16x8_t*)(WT + (size_t)(g * HH + j0 + (lr & 7)) * HH + k8);
    }
    int byt = ((lr * HH + k8) * 2) ^ ((lr & 7) << 4);
    *(bf16x8_t*)((char*)wl + byt) = v;
  }
}

// ---------- persistent encoder: 256 blocks x (16 batches x 8 cols x 3 gates) ----------
__global__ __launch_bounds__(512, 1) void k_enc3(
    const unsigned short* __restrict__ gx,   // [32][256][3072]
    const unsigned short* __restrict__ WhT,  // [3072][1024]
    unsigned short* __restrict__ ench,       // [32][256][1024]
    unsigned short* __restrict__ hg,         // [2][32][1024] device-coherent
    float* __restrict__ h0f,                 // [32][1024]
    unsigned* __restrict__ flags) {
  __shared__ __align__(16) unsigned short wl[32 * 1024];  // 64 KB
  __shared__ float gs[4][2][16][16];
  __shared__ float gg[3][16][8];
  __shared__ float hpf[16][8];
  const int tid = threadIdx.x, bid = blockIdx.x;
  const int wave = tid >> 6, lane = tid & 63;
  const int bh = bid >> 7, j0 = (bid & 127) * 8;
  const int kq = wave >> 1, nt = wave & 1;
  const int lk = (lane >> 4) * 8;
  stage_wslice(wl, WhT, j0, tid);
  if (tid < 128) hpf[tid >> 3][tid & 7] = 0.0f;
  __syncthreads();
  for (int t = 0; t < SSRC; ++t) {
    const unsigned short* hsrc = hg + (size_t)(t & 1) * (32 * HH);
    // K-split GEMM: wave (kq,nt); x rows = 16 batches of this half, sc1 loads
    f32x4_t acc = {};
    const int arow = bh * 16 + (lane & 15);
#pragma unroll
    for (int ks = 0; ks < 8; ++ks) {
      int kt = kq * 256 + ks * 32 + lk;
      bf16x8_t x = ald_bf16x8(hsrc + (size_t)arow * HH + kt);
      int byt = (((nt * 16 + (lane & 15)) * HH + kt) * 2) ^ ((lane & 7) << 4);
      bf16x8_t w8 = *(const bf16x8_t*)((const char*)wl + byt);
      acc = mfma16(x, w8, acc);
    }
#pragma unroll
    for (int r = 0; r < 4; ++r) gs[kq][nt][(lane >> 4) * 4 + r][lane & 15] = acc[r];
    __syncthreads();
    {
      int b = tid >> 5, c = tid & 31;
      if (c < 24) {
        int ntc = c >> 4, tcol = c & 15;
        gg[c >> 3][b][c & 7] =
            gs[0][ntc][b][tcol] + gs[1][ntc][b][tcol] + gs[2][ntc][b][tcol] + gs[3][ntc][b][tcol];
      }
    }
    __syncthreads();
    if (tid < 64) {
      int b = tid >> 2, jj = (tid & 3) * 2;
      int bg = bh * 16 + b;
      const unsigned short* gxp = gx + ((size_t)bg * SSRC + t) * (3 * HH) + j0 + jj;
      unsigned short hv[2];
      float hn[2];
#pragma unroll
      for (int u = 0; u < 2; ++u) {
        float xz = bf2f(gxp[u]), xr = bf2f(gxp[HH + u]), xh = bf2f(gxp[2 * HH + u]);
        float hz = gg[0][b][jj + u], hr = gg[1][b][jj + u], hh2 = gg[2][b][jj + u];
        float z = 1.f / (1.f + expf(-(xz + hz)));
        float r = 1.f / (1.f + expf(-(xr + hr)));
        float cand = tanhf(xh + r * hh2);
        hn[u] = z * hpf[b][jj + u] + (1.f - z) * cand;
        hpf[b][jj + u] = hn[u];
        hv[u] = f2bf(hn[u]);
      }
      unsigned pk = (unsigned)hv[0] | ((unsigned)hv[1] << 16);
      *(unsigned*)(ench + ((size_t)bg * SSRC + t) * HH + j0 + jj) = pk;
      ast32((unsigned*)(hg + (size_t)((t + 1) & 1) * (32 * HH) + bg * HH + j0 + jj), pk);
      if (t == SSRC - 1) {
        h0f[bg * HH + j0 + jj] = hn[0];
        h0f[bg * HH + j0 + jj + 1] = hn[1];
      }
    }
    arrive(flags, t + 1);
    if (t < SSRC - 1) pollbar(flags, t + 1);
  }
}

// ---------- persistent decoder: 256 blocks, attention (8/batch) + GEMM duties ----------
__global__ __launch_bounds__(512, 1) void k_dec3(
    const unsigned short* __restrict__ xpart,  // [32][64][3072]
    const unsigned short* __restrict__ WhDT,   // [3072][1024]
    const unsigned short* __restrict__ WxD2T,  // [3072][1024]
    const unsigned short* __restrict__ ench,   // [32][256][1024]
    const unsigned short* __restrict__ encW,   // [32][256][1024]
    const float* __restrict__ h0f,
    unsigned short* __restrict__ hg,           // [2][32][1024] device-coherent
    float* __restrict__ ctxf,                  // [2][32][1024] f32, unnormalized (atomics)
    float* __restrict__ denom,                 // [2][32]
    unsigned short* __restrict__ deco,         // [32][64][1024]
    unsigned* __restrict__ flags) {
  __shared__ __align__(16) unsigned short wl2[2 * 32 * 1024];  // 128 KB: [0]=WhD, [1]=WxD2
  __shared__ float gsA[4][2][16][16];
  __shared__ float gsB[4][2][16][16];
  __shared__ float gg[2][3][16][8];
  __shared__ float hpf[16][8];
  __shared__ __align__(16) unsigned short hbuf[HH];
  __shared__ float wt[32];
  __shared__ float inv[16];
  const int tid = threadIdx.x, bid = blockIdx.x;
  const int wave = tid >> 6, lane = tid & 63;
  const int bh = bid >> 7, j0 = (bid & 127) * 8;
  const int ab = bid >> 3, s0 = (bid & 7) * 32;
  const int kq = wave >> 1, nt = wave & 1;
  const int lk = (lane >> 4) * 8;
  stage_wslice(wl2, WhDT, j0, tid);
  stage_wslice(wl2 + 32 * 1024, WxD2T, j0, tid);
  if (tid < 128) hpf[tid >> 3][tid & 7] = h0f[(bh * 16 + (tid >> 3)) * HH + j0 + (tid & 7)];
  __syncthreads();
  unsigned gf = 0;
  for (int t = 0; t < SDEC; ++t) {
    const int cur = t & 1, nxt = cur ^ 1;
    // zero next-step accumulators (last read finished before bar2 of t-1)
    if (tid < 128) astf(&ctxf[nxt * (32 * HH) + bid * 128 + tid], 0.f);
    if (bid < 32 && tid == 0) astf(&denom[nxt * 32 + bid], 0.f);
    // load my attention batch's h row (sc1)
    if (tid < 128) {
      unsigned long long q = ald64(hg + (size_t)cur * (32 * HH) + ab * HH + tid * 8);
      *(unsigned long long*)(hbuf + tid * 8) = q;
      q = ald64(hg + (size_t)cur * (32 * HH) + ab * HH + tid * 8 + 4);
      *(unsigned long long*)(hbuf + tid * 8 + 4) = q;
    }
    __syncthreads();
    // scores for my 32 src rows (encW slice: L2-resident normal loads)
    {
      int r = wave * 4 + (lane >> 4);
      const unsigned short* er = encW + ((size_t)ab * SSRC + s0 + r) * HH;
      float dacc = 0.f;
#pragma unroll
      for (int it = 0; it < 8; ++it) {
        int k = it * 128 + (lane & 15) * 8;
        bf16x8_t e = *(const bf16x8_t*)(er + k);
        bf16x8_t h8 = *(const bf16x8_t*)(hbuf + k);
#pragma unroll
        for (int u = 0; u < 8; ++u)
          dacc += bf2f((unsigned short)e[u]) * bf2f((unsigned short)h8[u]);
      }
#pragma unroll
      for (int m = 1; m < 16; m <<= 1) dacc += __shfl_xor(dacc, m);
      if ((lane & 15) == 0) wt[r] = expf(dacc);  // scores O(1): no max subtraction
    }
    __syncthreads();
    if (tid == 0) {
      float ds = 0.f;
#pragma unroll
      for (int s = 0; s < 32; ++s) ds += wt[s];
      unsafeAtomicAdd(&denom[cur * 32 + ab], ds);
    }
    {
      int k2 = tid * 2;
      float a0 = 0.f, a1 = 0.f;
      const unsigned short* eb = ench + ((size_t)ab * SSRC + s0) * HH + k2;
#pragma unroll 4
      for (int s = 0; s < 32; ++s) {
        float w = wt[s];
        unsigned pk = *(const unsigned*)(eb + (size_t)s * HH);
        a0 += w * bf2f((unsigned short)(pk & 0xffffu));
        a1 += w * bf2f((unsigned short)(pk >> 16));
      }
      float* cp = ctxf + (size_t)cur * (32 * HH) + ab * HH + k2;
      unsafeAtomicAdd(cp, a0);
      unsafeAtomicAdd(cp + 1, a1);
    }
    // gh_h = h @ WhD (pre-barrier: depends only on h_t)
    {
      f32x4_t acc = {};
      const int arow = bh * 16 + (lane & 15);
      const unsigned short* hsrc = hg + (size_t)cur * (32 * HH);
#pragma unroll
      for (int ks = 0; ks < 8; ++ks) {
        int kt = kq * 256 + ks * 32 + lk;
        bf16x8_t x = ald_bf16x8(hsrc + (size_t)arow * HH + kt);
        int byt = (((nt * 16 + (lane & 15)) * HH + kt) * 2) ^ ((lane & 7) << 4);
        bf16x8_t w8 = *(const bf16x8_t*)((const char*)wl2 + byt);
        acc = mfma16(x, w8, acc);
      }
#pragma unroll
      for (int r = 0; r < 4; ++r) gsA[kq][nt][(lane >> 4) * 4 + r][lane & 15] = acc[r];
    }
    arrive(flags, gf + 1);
    pollbar(flags, gf + 1);
    gf++;
    // ---- phase B ----
    if (tid < 16) inv[tid] = 1.f / aldf(&denom[cur * 32 + bh * 16 + tid]);
    {
      f32x4_t acc = {};
      const int arow = bh * 16 + (lane & 15);
      const float* cb = ctxf + (size_t)cur * (32 * HH) + (size_t)arow * HH;
#pragma unroll
      for (int ks = 0; ks < 8; ++ks) {
        int kt = kq * 256 + ks * 32 + lk;
        bf16x8_t x = ald_f32x8_bf(cb + kt);
        int byt = ((32 * 1024 + (nt * 16 + (lane & 15)) * HH + kt) * 2) ^ ((lane & 7) << 4);
        bf16x8_t w8 = *(const bf16x8_t*)((const char*)wl2 + byt);
        acc = mfma16(x, w8, acc);
      }
#pragma unroll
      for (int r = 0; r < 4; ++r) gsB[kq][nt][(lane >> 4) * 4 + r][lane & 15] = acc[r];
    }
    __syncthreads();
    {
      int b = tid >> 5, c = tid & 31;
      if (c < 24) {
        int ntc = c >> 4, tcol = c & 15;
        gg[0][c >> 3][b][c & 7] =
            gsA[0][ntc][b][tcol] + gsA[1][ntc][b][tcol] + gsA[2][ntc][b][tcol] + gsA[3][ntc][b][tcol];
        gg[1][c >> 3][b][c & 7] =
            gsB[0][ntc][b][tcol] + gsB[1][ntc][b][tcol] + gsB[2][ntc][b][tcol] + gsB[3][ntc][b][tcol];
      }
    }
    __syncthreads();
    if (tid < 64) {
      int b = tid >> 2, jj = (tid & 3) * 2;
      int bg = bh * 16 + b;
      float iv = inv[b];
      const unsigned short* xp = xpart + ((size_t)bg * SDEC + t) * (3 * HH) + j0 + jj;
      unsigned short hv[2];
#pragma unroll
      for (int u = 0; u < 2; ++u) {
        float xz = bf2f(xp[u]) + gg[1][0][b][jj + u] * iv;
        float xr = bf2f(xp[HH + u]) + gg[1][1][b][jj + u] * iv;
        float xh = bf2f(xp[2 * HH + u]) + gg[1][2][b][jj + u] * iv;
        float hz = gg[0][0][b][jj + u], hr = gg[0][1][b][jj + u], hh2 = gg[0][2][b][jj + u];
        float z = 1.f / (1.f + expf(-(xz + hz)));
        float r = 1.f / (1.f + expf(-(xr + hr)));
        float cand = tanhf(xh + r * hh2);
        float hn = z * hpf[b][jj + u] + (1.f - z) * cand;
        hpf[b][jj + u] = hn;
        hv[u] = f2bf(hn);
      }
      unsigned pk = (unsigned)hv[0] | ((unsigned)hv[1] << 16);
      *(unsigned*)(deco + ((size_t)bg * SDEC + t) * HH + j0 + jj) = pk;
      ast32((unsigned*)(hg + (size_t)nxt * (32 * HH) + bg * HH + j0 + jj), pk);
    }
    arrive(flags, gf + 1);
    if (t < SDEC - 1) pollbar(flags, gf + 1);
    gf++;
  }
}

extern "C" void kernel_launch(void* const* d_in, const int* in_sizes, int n_in,
                              void* d_out, int out_size, void* d_ws, size_t ws_size,
                              hipStream_t stream) {
  const int* src_seq = (const int*)d_in[0];
  const int* dec_seq = (const int*)d_in[1];
  const float* emb = (const float*)d_in[2];
  const float* Wx_enc = (const float*)d_in[3];
  const float* Wh_enc = (const float*)d_in[4];
  const float* b_enc = (const float*)d_in[5];
  const float* Wx_dec = (const float*)d_in[6];
  const float* Wh_dec = (const float*)d_in[7];
  const float* b_dec = (const float*)d_in[8];
  const float* W_att = (const float*)d_in[9];
  const float* W_out = (const float*)d_in[10];
  const float* b_out = (const float*)d_in[11];

  // Single-phase scratch in d_out (~128 MB < 262 MB; overwritten by final GEMM).
  char* ob = (char*)d_out;
  size_t oo = 0;
  auto oalloc = [&](size_t bytes) {
    char* p = ob + oo;
    oo += (bytes + 255) & ~(size_t)255;
    return p;
  };
  unsigned short* WxTe = (unsigned short*)oalloc((size_t)3 * HH * EDIM * 2);
  unsigned short* WhTe = (unsigned short*)oalloc((size_t)3 * HH * HH * 2);
  unsigned short* WxD1T = (unsigned short*)oalloc((size_t)3 * HH * EDIM * 2);
  unsigned short* WxD2T = (unsigned short*)oalloc((size_t)3 * HH * HH * 2);
  unsigned short* WhDT = (unsigned short*)oalloc((size_t)3 * HH * HH * 2);
  unsigned short* Wattb = (unsigned short*)oalloc((size_t)HH * HH * 2);
  unsigned short* src_e = (unsigned short*)oalloc((size_t)BATCH * SSRC * EDIM * 2);
  unsigned short* dec_e = (unsigned short*)oalloc((size_t)BATCH * SDEC * EDIM * 2);
  unsigned short* gx_enc = (unsigned short*)oalloc((size_t)BATCH * SSRC * 3 * HH * 2);
  unsigned short* xpart = (unsigned short*)oalloc((size_t)BATCH * SDEC * 3 * HH * 2);
  unsigned short* ench = (unsigned short*)oalloc((size_t)BATCH * SSRC * HH * 2);
  unsigned short* encW = (unsigned short*)oalloc((size_t)BATCH * SSRC * HH * 2);

  // Alive during final GEMM -> d_ws (~70 MB).
  char* wb = (char*)d_ws;
  size_t wo = 0;
  auto walloc = [&](size_t bytes) {
    char* p = wb + wo;
    wo += (bytes + 255) & ~(size_t)255;
    return p;
  };
  unsigned short* WoutT = (unsigned short*)walloc((size_t)VOC * HH * 2);
  unsigned short* deco = (unsigned short*)walloc((size_t)BATCH * SDEC * HH * 2);
  unsigned short* hg = (unsigned short*)walloc((size_t)2 * BATCH * HH * 2);
  float* h0f = (float*)walloc(BATCH * HH * 4);
  float* ctxf = (float*)walloc((size_t)2 * BATCH * HH * 4);
  float* denom = (float*)walloc(2 * 32 * 4);
  unsigned* flags_e = (unsigned*)walloc(NBLK * 16 * 4);
  unsigned* flags_d = (unsigned*)walloc(NBLK * 16 * 4);
  if (wo > ws_size) return;

  dim3 tb(32, 8);
  k_transpose_bf16<<<dim3(3 * HH / 32, EDIM / 32), tb, 0, stream>>>(Wx_enc, WxTe, EDIM, 3 * HH);
  k_transpose_bf16<<<dim3(3 * HH / 32, HH / 32), tb, 0, stream>>>(Wh_enc, WhTe, HH, 3 * HH);
  k_transpose_bf16<<<dim3(3 * HH / 32, EDIM / 32), tb, 0, stream>>>(Wx_dec, WxD1T, EDIM, 3 * HH);
  k_transpose_bf16<<<dim3(3 * HH / 32, HH / 32), tb, 0, stream>>>(Wx_dec + (size_t)EDIM * 3 * HH,
                                                                  WxD2T, HH, 3 * HH);
  k_transpose_bf16<<<dim3(3 * HH / 32, HH / 32), tb, 0, stream>>>(Wh_dec, WhDT, HH, 3 * HH);
  k_transpose_bf16<<<dim3(VOC / 32, HH / 32), tb, 0, stream>>>(W_out, WoutT, HH, VOC);
  k_cast_bf16<<<(HH * HH / 4) / 256, 256, 0, stream>>>(W_att, Wattb, HH * HH);

  k_embed<<<BATCH * SSRC, 128, 0, stream>>>(src_seq, emb, src_e);
  k_embed<<<BATCH * SDEC, 128, 0, stream>>>(dec_seq, emb, dec_e);

  k_gemm_bt<1><<<dim3(3 * HH / 128, BATCH * SSRC / 128), 256, 0, stream>>>(
      src_e, WxTe, b_enc, gx_enc, BATCH * SSRC, 3 * HH, EDIM);
  k_gemm_bt<1><<<dim3(3 * HH / 128, BATCH * SDEC / 128), 256, 0, stream>>>(
      dec_e, WxD1T, b_dec, xpart, BATCH * SDEC, 3 * HH, EDIM);

  hipMemsetAsync(hg, 0, (size_t)2 * BATCH * HH * 2, stream);
  hipMemsetAsync(ctxf, 0, (size_t)2 * BATCH * HH * 4, stream);
  hipMemsetAsync(denom, 0, 2 * 32 * 4, stream);
  hipMemsetAsync(flags_e, 0, NBLK * 16 * 4 * 2, stream);  // both flag arrays (contiguous)

  k_enc3<<<NBLK, 512, 0, stream>>>(gx_enc, WhTe, ench, hg, h0f, flags_e);

  // encW = ench @ W_att^T  (scores reassociation)
  k_gemm_bt<1><<<dim3(HH / 128, BATCH * SSRC / 128), 256, 0, stream>>>(
      ench, Wattb, nullptr, encW, BATCH * SSRC, HH, HH);

  k_dec3<<<NBLK, 512, 0, stream>>>(xpart, WhDT, WxD2T, ench, encW, h0f, hg, ctxf, denom, deco,
                                   flags_d);

  k_gemm_bt<0><<<dim3(VOC / 128, BATCH * SDEC / 128), 256, 0, stream>>>(
      deco, WoutT, b_out, d_out, BATCH * SDEC, VOC, HH);
}

// Round 5
// 2584.318 us; speedup vs baseline: 3.0829x; 1.3696x over previous
//
#include <hip/hip_runtime.h>
#include <hip/hip_bf16.h>

#define HH 1024
#define BATCH 32
#define SSRC 256
#define SDEC 64
#define EDIM 512
#define VOC 32000
#define NBLK 256

typedef __attribute__((ext_vector_type(8))) short bf16x8_t;
typedef __attribute__((ext_vector_type(4))) float f32x4_t;

__device__ __forceinline__ float bf2f(unsigned short u) {
  union { float f; unsigned int i; } c; c.i = ((unsigned int)u) << 16; return c.f;
}
__device__ __forceinline__ unsigned short f2bf(float f) {
  union { float f; unsigned int i; } c; c.f = f;
  unsigned int r = c.i + 0x7fffu + ((c.i >> 16) & 1u);
  return (unsigned short)(r >> 16);
}
__device__ __forceinline__ f32x4_t mfma16(bf16x8_t a, bf16x8_t b, f32x4_t c) {
  return __builtin_amdgcn_mfma_f32_16x16x32_bf16(a, b, c, 0, 0, 0);
}

// ---- device-coherent (sc1) accessors: bypass non-coherent per-XCD L2, NO fences ----
__device__ __forceinline__ unsigned long long ald64(const void* p) {
  return __hip_atomic_load((const unsigned long long*)p, __ATOMIC_RELAXED,
                           __HIP_MEMORY_SCOPE_AGENT);
}
__device__ __forceinline__ void ast32(unsigned* p, unsigned v) {
  __hip_atomic_store(p, v, __ATOMIC_RELAXED, __HIP_MEMORY_SCOPE_AGENT);
}
__device__ __forceinline__ unsigned ald32(const unsigned* p) {
  return __hip_atomic_load(p, __ATOMIC_RELAXED, __HIP_MEMORY_SCOPE_AGENT);
}
__device__ __forceinline__ void astf(float* p, float v) {
  __hip_atomic_store(p, v, __ATOMIC_RELAXED, __HIP_MEMORY_SCOPE_AGENT);
}
__device__ __forceinline__ float aldf(const float* p) {
  return __hip_atomic_load(p, __ATOMIC_RELAXED, __HIP_MEMORY_SCOPE_AGENT);
}
__device__ __forceinline__ bf16x8_t ald_bf16x8(const unsigned short* p) {
  union { unsigned long long q[2]; bf16x8_t v; } u;
  u.q[0] = ald64(p);
  u.q[1] = ald64(p + 4);
  return u.v;
}
__device__ __forceinline__ bf16x8_t ald_f32x8_bf(const float* p) {
  union { unsigned long long q; float f[2]; } a, b, c, d;
  a.q = ald64(p); b.q = ald64(p + 2); c.q = ald64(p + 4); d.q = ald64(p + 6);
  bf16x8_t r;
  r[0] = (short)f2bf(a.f[0]); r[1] = (short)f2bf(a.f[1]);
  r[2] = (short)f2bf(b.f[0]); r[3] = (short)f2bf(b.f[1]);
  r[4] = (short)f2bf(c.f[0]); r[5] = (short)f2bf(c.f[1]);
  r[6] = (short)f2bf(d.f[0]); r[7] = (short)f2bf(d.f[1]);
  return r;
}

// ---- fence-free flag barrier over a 128-block group ----
__device__ __forceinline__ void arrive(unsigned* fl, unsigned g1, int slot) {
  asm volatile("s_waitcnt vmcnt(0)" ::: "memory");  // my sc1 stores/atomics/loads done
  __syncthreads();                                  // whole block done
  if (threadIdx.x == 0) ast32(&fl[slot * 16], g1);
}
__device__ __forceinline__ void pollbar(const unsigned* fl, unsigned g1) {
  if (threadIdx.x < 64) {
    const int l = threadIdx.x;
    while (true) {
      unsigned a = ald32(&fl[l * 16]);
      unsigned b = ald32(&fl[(l + 64) * 16]);
      if (__all((a >= g1) && (b >= g1))) break;
      __builtin_amdgcn_s_sleep(1);
    }
  }
  __syncthreads();
  asm volatile("" ::: "memory");
}

// ---------- transpose f32 (K,N) -> bf16 (N,K) ----------
__global__ void k_transpose_bf16(const float* __restrict__ in, unsigned short* __restrict__ out,
                                 int K, int N) {
  __shared__ float tile[32][33];
  int n0 = blockIdx.x * 32, k0 = blockIdx.y * 32;
  int tx = threadIdx.x, ty = threadIdx.y;
#pragma unroll
  for (int i = 0; i < 4; i++)
    tile[ty + i * 8][tx] = in[(size_t)(k0 + ty + i * 8) * N + (n0 + tx)];
  __syncthreads();
#pragma unroll
  for (int i = 0; i < 4; i++)
    out[(size_t)(n0 + ty + i * 8) * K + (k0 + tx)] = f2bf(tile[tx][ty + i * 8]);
}

// ---------- elementwise cast f32 -> bf16 ----------
__global__ void k_cast_bf16(const float* __restrict__ in, unsigned short* __restrict__ out, int n) {
  int i = (blockIdx.x * blockDim.x + threadIdx.x) * 4;
  if (i < n) {
    float4 v = *(const float4*)(in + i);
    out[i] = f2bf(v.x); out[i + 1] = f2bf(v.y); out[i + 2] = f2bf(v.z); out[i + 3] = f2bf(v.w);
  }
}

// ---------- embedding gather -> bf16 ----------
__global__ void k_embed(const int* __restrict__ seq, const float* __restrict__ emb,
                        unsigned short* __restrict__ out) {
  int t = blockIdx.x;
  int row = seq[t];
  const float* s = emb + (size_t)row * EDIM;
  unsigned short* d = out + (size_t)t * EDIM;
  for (int e = threadIdx.x; e < EDIM; e += blockDim.x) d[e] = f2bf(s[e]);
}

// ---------- big GEMM: C[M,N] = A[M,K](bf16) * B^T[N,K](bf16) + bias ----------
template <int OUT_BF16>
__global__ __launch_bounds__(256) void k_gemm_bt(const unsigned short* __restrict__ A,
                                                 const unsigned short* __restrict__ B,
                                                 const float* __restrict__ bias,
                                                 void* __restrict__ Cv, int M, int N, int K) {
  __shared__ unsigned short As[128 * 32];
  __shared__ unsigned short Bs[128 * 32];
  const int tid = threadIdx.x;
  const int wave = tid >> 6, lane = tid & 63;
  const int row0 = blockIdx.y * 128, col0 = blockIdx.x * 128;
  const int wr = (wave >> 1) * 64, wc = (wave & 1) * 64;
  const int lrow = lane & 15, lk8 = (lane >> 4) * 8;
  f32x4_t acc[4][4] = {};
  const int c1 = wave, c2 = wave + 4;
  const int sr1 = c1 * 16 + (lane >> 2), sr2 = c2 * 16 + (lane >> 2);
  const int sk = (lane & 3) * 8;
  for (int kt = 0; kt < K; kt += 32) {
    __builtin_amdgcn_global_load_lds(
        (const __attribute__((address_space(1))) unsigned int*)(A + (size_t)(row0 + sr1) * K + kt + sk),
        (__attribute__((address_space(3))) unsigned int*)(As + c1 * 512), 16, 0, 0);
    __builtin_amdgcn_global_load_lds(
        (const __attribute__((address_space(1))) unsigned int*)(A + (size_t)(row0 + sr2) * K + kt + sk),
        (__attribute__((address_space(3))) unsigned int*)(As + c2 * 512), 16, 0, 0);
    __builtin_amdgcn_global_load_lds(
        (const __attribute__((address_space(1))) unsigned int*)(B + (size_t)(col0 + sr1) * K + kt + sk),
        (__attribute__((address_space(3))) unsigned int*)(Bs + c1 * 512), 16, 0, 0);
    __builtin_amdgcn_global_load_lds(
        (const __attribute__((address_space(1))) unsigned int*)(B + (size_t)(col0 + sr2) * K + kt + sk),
        (__attribute__((address_space(3))) unsigned int*)(Bs + c2 * 512), 16, 0, 0);
    __syncthreads();
    bf16x8_t af[4], bfr[4];
#pragma unroll
    for (int i = 0; i < 4; i++) {
      af[i] = *(const bf16x8_t*)(As + (wr + i * 16 + lrow) * 32 + lk8);
      bfr[i] = *(const bf16x8_t*)(Bs + (wc + i * 16 + lrow) * 32 + lk8);
    }
#pragma unroll
    for (int i = 0; i < 4; i++)
#pragma unroll
      for (int j = 0; j < 4; j++) acc[i][j] = mfma16(af[i], bfr[j], acc[i][j]);
    __syncthreads();
  }
#pragma unroll
  for (int j = 0; j < 4; j++) {
    int col = col0 + wc + j * 16 + lrow;
    float bv = bias ? bias[col] : 0.0f;
#pragma unroll
    for (int i = 0; i < 4; i++) {
#pragma unroll
      for (int r = 0; r < 4; r++) {
        int row = row0 + wr + i * 16 + (lane >> 4) * 4 + r;
        float v = acc[i][j][r] + bv;
        if (OUT_BF16)
          ((unsigned short*)Cv)[(size_t)row * N + col] = f2bf(v);
        else
          ((float*)Cv)[(size_t)row * N + col] = v;
      }
    }
  }
}

// Weight-slice LDS staging: 32 rows (z0-7,r0-7,hh0-7,pad), XOR-swizzled.
__device__ __forceinline__ void stage_wslice(unsigned short* wl, const unsigned short* WT,
                                             int j0, int tid) {
  for (int i = tid; i < 32 * 128; i += 512) {
    int lr = i >> 7, k8 = (i & 127) * 8;
    bf16x8_t v = {};
    if (lr < 24) {
      int g = lr >> 3;
      v = *(const bf16x8_t*)(WT + (size_t)(g * HH + j0 + (lr & 7)) * HH + k8);
    }
    int byt = ((lr * HH + k8) * 2) ^ ((lr & 7) << 4);
    *(bf16x8_t*)((char*)wl + byt) = v;
  }
}

// ---------- persistent encoder: 2 groups x 128 blocks; 1 flag-bar/step ----------
__global__ __launch_bounds__(512, 1) void k_enc4(
    const unsigned short* __restrict__ gx,   // [32][256][3072]
    const unsigned short* __restrict__ WhT,  // [3072][1024]
    unsigned short* __restrict__ ench,       // [32][256][1024]
    unsigned short* __restrict__ hg,         // [2][32][1024] device-coherent
    float* __restrict__ h0f,                 // [32][1024]
    unsigned* __restrict__ flags) {
  __shared__ __align__(16) unsigned short wl[32 * 1024];  // 64 KB
  __shared__ float gs[8][2][16][16];
  __shared__ float gg[3][16][8];
  __shared__ float hpf[16][8];
  __shared__ __align__(16) unsigned short gxl[2][3][16][8];
  const int tid = threadIdx.x, bid = blockIdx.x;
  const int wave = tid >> 6, lane = tid & 63;
  const int bh = bid >> 7, j0 = (bid & 127) * 8;
  const int slot = bid & 127;
  unsigned* fl = flags + bh * 128 * 16;
  const int kq = wave;  // 8-way K split, no duplication
  const int lk = (lane >> 4) * 8;
  stage_wslice(wl, WhT, j0, tid);
  if (tid < 128) hpf[tid >> 3][tid & 7] = 0.0f;
  if (tid < 48) {  // prefetch gx[0]
    int gat = tid >> 4, bb = tid & 15;
    *(bf16x8_t*)&gxl[0][gat][bb][0] =
        *(const bf16x8_t*)(gx + ((size_t)(bh * 16 + bb) * SSRC + 0) * (3 * HH) + gat * HH + j0);
  }
  __syncthreads();
  for (int t = 0; t < SSRC; ++t) {
    const int cur = t & 1;
    // prefetch gx[t+1] into LDS (off critical path)
    if (tid < 48) {
      int tt = (t + 1 < SSRC) ? t + 1 : t;
      int gat = tid >> 4, bb = tid & 15;
      *(bf16x8_t*)&gxl[tt & 1][gat][bb][0] =
          *(const bf16x8_t*)(gx + ((size_t)(bh * 16 + bb) * SSRC + tt) * (3 * HH) + gat * HH + j0);
    }
    // K-split GEMM: wave kq owns K slice [kq*128, kq*128+128)
    const unsigned short* hsrc = hg + (size_t)cur * (32 * HH);
    f32x4_t a0 = {}, a1 = {};
    {
      const unsigned short* hrow = hsrc + (size_t)(bh * 16 + (lane & 15)) * HH + kq * 128 + lk;
#pragma unroll
      for (int ks = 0; ks < 4; ++ks) {
        bf16x8_t x = ald_bf16x8(hrow + ks * 32);
        int k = kq * 128 + ks * 32 + lk;
        int byt0 = (((lane & 15) * HH + k) * 2) ^ ((lane & 7) << 4);
        int byt1 = (((16 + (lane & 15)) * HH + k) * 2) ^ ((lane & 7) << 4);
        bf16x8_t w0 = *(const bf16x8_t*)((const char*)wl + byt0);
        bf16x8_t w1 = *(const bf16x8_t*)((const char*)wl + byt1);
        a0 = mfma16(x, w0, a0);
        a1 = mfma16(x, w1, a1);
      }
    }
#pragma unroll
    for (int r = 0; r < 4; ++r) {
      gs[kq][0][(lane >> 4) * 4 + r][lane & 15] = a0[r];
      gs[kq][1][(lane >> 4) * 4 + r][lane & 15] = a1[r];
    }
    __syncthreads();
    {
      int b = tid >> 5, c = tid & 31;
      if (c < 24) {
        int ntc = c >> 4, tcol = c & 15;
        float s = 0.f;
#pragma unroll
        for (int q = 0; q < 8; ++q) s += gs[q][ntc][b][tcol];
        gg[c >> 3][b][c & 7] = s;
      }
    }
    __syncthreads();
    if (tid < 64) {
      int b = tid >> 2, jj = (tid & 3) * 2;
      int bg = bh * 16 + b;
      unsigned short hv[2];
      float hn[2];
#pragma unroll
      for (int u = 0; u < 2; ++u) {
        float xz = bf2f(gxl[cur][0][b][jj + u]);
        float xr = bf2f(gxl[cur][1][b][jj + u]);
        float xh = bf2f(gxl[cur][2][b][jj + u]);
        float hz = gg[0][b][jj + u], hr = gg[1][b][jj + u], hh2 = gg[2][b][jj + u];
        float z = 1.f / (1.f + expf(-(xz + hz)));
        float r = 1.f / (1.f + expf(-(xr + hr)));
        float cand = tanhf(xh + r * hh2);
        hn[u] = z * hpf[b][jj + u] + (1.f - z) * cand;
        hpf[b][jj + u] = hn[u];
        hv[u] = f2bf(hn[u]);
      }
      unsigned pk = (unsigned)hv[0] | ((unsigned)hv[1] << 16);
      *(unsigned*)(ench + ((size_t)bg * SSRC + t) * HH + j0 + jj) = pk;
      ast32((unsigned*)(hg + (size_t)(cur ^ 1) * (32 * HH) + bg * HH + j0 + jj), pk);
      if (t == SSRC - 1) {
        h0f[bg * HH + j0 + jj] = hn[0];
        h0f[bg * HH + j0 + jj + 1] = hn[1];
      }
    }
    arrive(fl, t + 1, slot);
    if (t < SSRC - 1) pollbar(fl, t + 1);
  }
}

// ---------- persistent decoder: 2 groups x 128 blocks; 2 flag-bars/step ----------
__global__ __launch_bounds__(512, 1) void k_dec4(
    const unsigned short* __restrict__ xpart,  // [32][64][3072]
    const unsigned short* __restrict__ WhDT,   // [3072][1024]
    const unsigned short* __restrict__ WxD2T,  // [3072][1024]
    const unsigned short* __restrict__ ench,   // [32][256][1024]
    const unsigned short* __restrict__ encW,   // [32][256][1024]
    const float* __restrict__ h0f,
    unsigned short* __restrict__ hg,           // [2][32][1024] device-coherent
    float* __restrict__ ctxf,                  // [2][32][1024] f32 (atomics)
    float* __restrict__ denom,                 // [2][32]
    unsigned short* __restrict__ deco,         // [32][64][1024]
    unsigned* __restrict__ flags) {
  __shared__ __align__(16) unsigned short wl2[2 * 32 * 1024];  // 128 KB: [0]=WhD, [1]=WxD2
  __shared__ float gs[8][2][16][16];                           // reused by both phases
  __shared__ float ggA[3][16][8];
  __shared__ float ggB[3][16][8];
  __shared__ float hpf[16][8];
  __shared__ __align__(16) unsigned short hbuf[HH];
  __shared__ float wt[32];
  __shared__ float inv[16];
  __shared__ __align__(16) unsigned short xpl[2][3][16][8];
  const int tid = threadIdx.x, bid = blockIdx.x;
  const int wave = tid >> 6, lane = tid & 63;
  const int bh = bid >> 7, j0 = (bid & 127) * 8;
  const int slot = bid & 127;
  unsigned* fl = flags + bh * 128 * 16;
  const int ab = bid >> 3, s0 = (bid & 7) * 32;  // attention duty (in-group: ab>>4 == bh)
  const int kq = wave;
  const int lk = (lane >> 4) * 8;
  stage_wslice(wl2, WhDT, j0, tid);
  stage_wslice(wl2 + 32 * 1024, WxD2T, j0, tid);
  if (tid < 128) hpf[tid >> 3][tid & 7] = h0f[(bh * 16 + (tid >> 3)) * HH + j0 + (tid & 7)];
  if (tid < 48) {  // prefetch xpart[0]
    int gat = tid >> 4, bb = tid & 15;
    *(bf16x8_t*)&xpl[0][gat][bb][0] =
        *(const bf16x8_t*)(xpart + ((size_t)(bh * 16 + bb) * SDEC + 0) * (3 * HH) + gat * HH + j0);
  }
  __syncthreads();
  unsigned gf = 0;
  for (int t = 0; t < SDEC; ++t) {
    const int cur = t & 1, nxt = cur ^ 1;
    // prefetch xpart[t+1]
    if (tid < 48) {
      int tt = (t + 1 < SDEC) ? t + 1 : t;
      int gat = tid >> 4, bb = tid & 15;
      *(bf16x8_t*)&xpl[tt & 1][gat][bb][0] =
          *(const bf16x8_t*)(xpart + ((size_t)(bh * 16 + bb) * SDEC + tt) * (3 * HH) + gat * HH + j0);
    }
    // zero next-step accumulators (in-group ownership)
    if (tid < 128) astf(&ctxf[(size_t)nxt * (32 * HH) + (size_t)bid * 128 + tid], 0.f);
    if (slot < 16 && tid == 0) astf(&denom[nxt * 32 + bh * 16 + slot], 0.f);
    // my attention batch's h row (sc1)
    if (tid < 128) {
      unsigned long long q = ald64(hg + (size_t)cur * (32 * HH) + ab * HH + tid * 8);
      *(unsigned long long*)(hbuf + tid * 8) = q;
      q = ald64(hg + (size_t)cur * (32 * HH) + ab * HH + tid * 8 + 4);
      *(unsigned long long*)(hbuf + tid * 8 + 4) = q;
    }
    __syncthreads();
    // scores for my 32 src rows (encW: cached, L2-resident)
    {
      int r = wave * 4 + (lane >> 4);
      const unsigned short* er = encW + ((size_t)ab * SSRC + s0 + r) * HH;
      float dacc = 0.f;
#pragma unroll
      for (int it = 0; it < 8; ++it) {
        int k = it * 128 + (lane & 15) * 8;
        bf16x8_t e = *(const bf16x8_t*)(er + k);
        bf16x8_t h8 = *(const bf16x8_t*)(hbuf + k);
#pragma unroll
        for (int u = 0; u < 8; ++u)
          dacc += bf2f((unsigned short)e[u]) * bf2f((unsigned short)h8[u]);
      }
#pragma unroll
      for (int m = 1; m < 16; m <<= 1) dacc += __shfl_xor(dacc, m);
      if ((lane & 15) == 0) wt[r] = expf(dacc);  // scores O(1): no max subtraction
    }
    __syncthreads();
    if (tid == 0) {
      float ds = 0.f;
#pragma unroll
      for (int s = 0; s < 32; ++s) ds += wt[s];
      unsafeAtomicAdd(&denom[cur * 32 + ab], ds);
    }
    {
      int k2 = tid * 2;
      float a0 = 0.f, a1 = 0.f;
      const unsigned short* eb = ench + ((size_t)ab * SSRC + s0) * HH + k2;
#pragma unroll 4
      for (int s = 0; s < 32; ++s) {
        float w = wt[s];
        unsigned pk = *(const unsigned*)(eb + (size_t)s * HH);
        a0 += w * bf2f((unsigned short)(pk & 0xffffu));
        a1 += w * bf2f((unsigned short)(pk >> 16));
      }
      float* cp = ctxf + (size_t)cur * (32 * HH) + ab * HH + k2;
      unsafeAtomicAdd(cp, a0);
      unsafeAtomicAdd(cp + 1, a1);
    }
    // gh_h = h @ WhD (local result; overlaps barrier)
    {
      const unsigned short* hrow =
          hg + (size_t)cur * (32 * HH) + (size_t)(bh * 16 + (lane & 15)) * HH + kq * 128 + lk;
      f32x4_t a0 = {}, a1 = {};
#pragma unroll
      for (int ks = 0; ks < 4; ++ks) {
        bf16x8_t x = ald_bf16x8(hrow + ks * 32);
        int k = kq * 128 + ks * 32 + lk;
        int byt0 = (((lane & 15) * HH + k) * 2) ^ ((lane & 7) << 4);
        int byt1 = (((16 + (lane & 15)) * HH + k) * 2) ^ ((lane & 7) << 4);
        bf16x8_t w0 = *(const bf16x8_t*)((const char*)wl2 + byt0);
        bf16x8_t w1 = *(const bf16x8_t*)((const char*)wl2 + byt1);
        a0 = mfma16(x, w0, a0);
        a1 = mfma16(x, w1, a1);
      }
#pragma unroll
      for (int r = 0; r < 4; ++r) {
        gs[kq][0][(lane >> 4) * 4 + r][lane & 15] = a0[r];
        gs[kq][1][(lane >> 4) * 4 + r][lane & 15] = a1[r];
      }
    }
    arrive(fl, gf + 1, slot);
    pollbar(fl, gf + 1);
    gf++;
    // reduce gs -> ggA, then reuse gs for phase B
    {
      int b = tid >> 5, c = tid & 31;
      if (c < 24) {
        int ntc = c >> 4, tcol = c & 15;
        float s = 0.f;
#pragma unroll
        for (int q = 0; q < 8; ++q) s += gs[q][ntc][b][tcol];
        ggA[c >> 3][b][c & 7] = s;
      }
    }
    if (tid < 16) inv[tid] = 1.f / aldf(&denom[cur * 32 + bh * 16 + tid]);
    __syncthreads();
    // phase B: gh_c = ctx_unnorm @ WxD2
    {
      const float* cb =
          ctxf + (size_t)cur * (32 * HH) + (size_t)(bh * 16 + (lane & 15)) * HH + kq * 128 + lk;
      f32x4_t a0 = {}, a1 = {};
#pragma unroll
      for (int ks = 0; ks < 4; ++ks) {
        bf16x8_t x = ald_f32x8_bf(cb + ks * 32);
        int k = kq * 128 + ks * 32 + lk;
        int byt0 = ((32 * 1024 + (lane & 15) * HH + k) * 2) ^ ((lane & 7) << 4);
        int byt1 = ((32 * 1024 + (16 + (lane & 15)) * HH + k) * 2) ^ ((lane & 7) << 4);
        bf16x8_t w0 = *(const bf16x8_t*)((const char*)wl2 + byt0);
        bf16x8_t w1 = *(const bf16x8_t*)((const char*)wl2 + byt1);
        a0 = mfma16(x, w0, a0);
        a1 = mfma16(x, w1, a1);
      }
#pragma unroll
      for (int r = 0; r < 4; ++r) {
        gs[kq][0][(lane >> 4) * 4 + r][lane & 15] = a0[r];
        gs[kq][1][(lane >> 4) * 4 + r][lane & 15] = a1[r];
      }
    }
    __syncthreads();
    {
      int b = tid >> 5, c = tid & 31;
      if (c < 24) {
        int ntc = c >> 4, tcol = c & 15;
        float s = 0.f;
#pragma unroll
        for (int q = 0; q < 8; ++q) s += gs[q][ntc][b][tcol];
        ggB[c >> 3][b][c & 7] = s;
      }
    }
    __syncthreads();
    if (tid < 64) {
      int b = tid >> 2, jj = (tid & 3) * 2;
      int bg = bh * 16 + b;
      float iv = inv[b];
      unsigned short hv[2];
#pragma unroll
      for (int u = 0; u < 2; ++u) {
        float xz = bf2f(xpl[cur][0][b][jj + u]) + ggB[0][b][jj + u] * iv;
        float xr = bf2f(xpl[cur][1][b][jj + u]) + ggB[1][b][jj + u] * iv;
        float xh = bf2f(xpl[cur][2][b][jj + u]) + ggB[2][b][jj + u] * iv;
        float hz = ggA[0][b][jj + u], hr = ggA[1][b][jj + u], hh2 = ggA[2][b][jj + u];
        float z = 1.f / (1.f + expf(-(xz + hz)));
        float r = 1.f / (1.f + expf(-(xr + hr)));
        float cand = tanhf(xh + r * hh2);
        float hn = z * hpf[b][jj + u] + (1.f - z) * cand;
        hpf[b][jj + u] = hn;
        hv[u] = f2bf(hn);
      }
      unsigned pk = (unsigned)hv[0] | ((unsigned)hv[1] << 16);
      *(unsigned*)(deco + ((size_t)bg * SDEC + t) * HH + j0 + jj) = pk;
      ast32((unsigned*)(hg + (size_t)nxt * (32 * HH) + bg * HH + j0 + jj), pk);
    }
    arrive(fl, gf + 1, slot);
    if (t < SDEC - 1) pollbar(fl, gf + 1);
    gf++;
  }
}

extern "C" void kernel_launch(void* const* d_in, const int* in_sizes, int n_in,
                              void* d_out, int out_size, void* d_ws, size_t ws_size,
                              hipStream_t stream) {
  const int* src_seq = (const int*)d_in[0];
  const int* dec_seq = (const int*)d_in[1];
  const float* emb = (const float*)d_in[2];
  const float* Wx_enc = (const float*)d_in[3];
  const float* Wh_enc = (const float*)d_in[4];
  const float* b_enc = (const float*)d_in[5];
  const float* Wx_dec = (const float*)d_in[6];
  const float* Wh_dec = (const float*)d_in[7];
  const float* b_dec = (const float*)d_in[8];
  const float* W_att = (const float*)d_in[9];
  const float* W_out = (const float*)d_in[10];
  const float* b_out = (const float*)d_in[11];

  // Single-phase scratch in d_out (~128 MB < 262 MB; overwritten by final GEMM).
  char* ob = (char*)d_out;
  size_t oo = 0;
  auto oalloc = [&](size_t bytes) {
    char* p = ob + oo;
    oo += (bytes + 255) & ~(size_t)255;
    return p;
  };
  unsigned short* WxTe = (unsigned short*)oalloc((size_t)3 * HH * EDIM * 2);
  unsigned short* WhTe = (unsigned short*)oalloc((size_t)3 * HH * HH * 2);
  unsigned short* WxD1T = (unsigned short*)oalloc((size_t)3 * HH * EDIM * 2);
  unsigned short* WxD2T = (unsigned short*)oalloc((size_t)3 * HH * HH * 2);
  unsigned short* WhDT = (unsigned short*)oalloc((size_t)3 * HH * HH * 2);
  unsigned short* Wattb = (unsigned short*)oalloc((size_t)HH * HH * 2);
  unsigned short* src_e = (unsigned short*)oalloc((size_t)BATCH * SSRC * EDIM * 2);
  unsigned short* dec_e = (unsigned short*)oalloc((size_t)BATCH * SDEC * EDIM * 2);
  unsigned short* gx_enc = (unsigned short*)oalloc((size_t)BATCH * SSRC * 3 * HH * 2);
  unsigned short* xpart = (unsigned short*)oalloc((size_t)BATCH * SDEC * 3 * HH * 2);
  unsigned short* ench = (unsigned short*)oalloc((size_t)BATCH * SSRC * HH * 2);
  unsigned short* encW = (unsigned short*)oalloc((size_t)BATCH * SSRC * HH * 2);

  // Alive during final GEMM -> d_ws (~70 MB).
  char* wb = (char*)d_ws;
  size_t wo = 0;
  auto walloc = [&](size_t bytes) {
    char* p = wb + wo;
    wo += (bytes + 255) & ~(size_t)255;
    return p;
  };
  unsigned short* WoutT = (unsigned short*)walloc((size_t)VOC * HH * 2);
  unsigned short* deco = (unsigned short*)walloc((size_t)BATCH * SDEC * HH * 2);
  unsigned short* hg = (unsigned short*)walloc((size_t)2 * BATCH * HH * 2);
  float* h0f = (float*)walloc(BATCH * HH * 4);
  float* ctxf = (float*)walloc((size_t)2 * BATCH * HH * 4);
  float* denom = (float*)walloc(2 * 32 * 4);
  unsigned* flags_e = (unsigned*)walloc(NBLK * 16 * 4);
  unsigned* flags_d = (unsigned*)walloc(NBLK * 16 * 4);
  if (wo > ws_size) return;

  dim3 tb(32, 8);
  k_transpose_bf16<<<dim3(3 * HH / 32, EDIM / 32), tb, 0, stream>>>(Wx_enc, WxTe, EDIM, 3 * HH);
  k_transpose_bf16<<<dim3(3 * HH / 32, HH / 32), tb, 0, stream>>>(Wh_enc, WhTe, HH, 3 * HH);
  k_transpose_bf16<<<dim3(3 * HH / 32, EDIM / 32), tb, 0, stream>>>(Wx_dec, WxD1T, EDIM, 3 * HH);
  k_transpose_bf16<<<dim3(3 * HH / 32, HH / 32), tb, 0, stream>>>(Wx_dec + (size_t)EDIM * 3 * HH,
                                                                  WxD2T, HH, 3 * HH);
  k_transpose_bf16<<<dim3(3 * HH / 32, HH / 32), tb, 0, stream>>>(Wh_dec, WhDT, HH, 3 * HH);
  k_transpose_bf16<<<dim3(VOC / 32, HH / 32), tb, 0, stream>>>(W_out, WoutT, HH, VOC);
  k_cast_bf16<<<(HH * HH / 4) / 256, 256, 0, stream>>>(W_att, Wattb, HH * HH);

  k_embed<<<BATCH * SSRC, 128, 0, stream>>>(src_seq, emb, src_e);
  k_embed<<<BATCH * SDEC, 128, 0, stream>>>(dec_seq, emb, dec_e);

  k_gemm_bt<1><<<dim3(3 * HH / 128, BATCH * SSRC / 128), 256, 0, stream>>>(
      src_e, WxTe, b_enc, gx_enc, BATCH * SSRC, 3 * HH, EDIM);
  k_gemm_bt<1><<<dim3(3 * HH / 128, BATCH * SDEC / 128), 256, 0, stream>>>(
      dec_e, WxD1T, b_dec, xpart, BATCH * SDEC, 3 * HH, EDIM);

  hipMemsetAsync(hg, 0, (size_t)2 * BATCH * HH * 2, stream);
  hipMemsetAsync(ctxf, 0, (size_t)2 * BATCH * HH * 4, stream);
  hipMemsetAsync(denom, 0, 2 * 32 * 4, stream);
  hipMemsetAsync(flags_e, 0, NBLK * 16 * 4 * 2, stream);  // both flag arrays (contiguous)

  k_enc4<<<NBLK, 512, 0, stream>>>(gx_enc, WhTe, ench, hg, h0f, flags_e);

  // encW = ench @ W_att^T  (scores reassociation)
  k_gemm_bt<1><<<dim3(HH / 128, BATCH * SSRC / 128), 256, 0, stream>>>(
      ench, Wattb, nullptr, encW, BATCH * SSRC, HH, HH);

  k_dec4<<<NBLK, 512, 0, stream>>>(xpart, WhDT, WxD2T, ench, encW, h0f, hg, ctxf, denom, deco,
                                   flags_d);

  k_gemm_bt<0><<<dim3(VOC / 128, BATCH * SDEC / 128), 256, 0, stream>>>(
      deco, WoutT, b_out, d_out, BATCH * SDEC, VOC, HH);
}